// Round 6
// baseline (706.305 us; speedup 1.0000x reference)
//
#include <hip/hip_runtime.h>
#include <hip/hip_cooperative_groups.h>
#include <math.h>

#define NN 8192        // n_nodes
#define NE 262144      // edges per adjacency list
#define TOTAL (2*NE)   // 524288 = 2048 blocks * 256 threads
#define CAP 128        // bucket capacity per row (row count max ~95 for this input)
#define HALF 4096      // columns per half-row tile (16 KB LDS -> 8 blocks/CU co-resident)

typedef float f4 __attribute__((ext_vector_type(4)));

struct Pair { int c; float v; };

// Workspace layout (bytes):
//   [0, 32768)       cnt[8192]
//   [32768, 32772)   ovf_cnt
//   [65536, +8MB)    bucket Pair[8192][128]
//   [65536+8MB, +128KB) ovf int4[8192]
#define BK_OFF 65536
#define OV_OFF (BK_OFF + (size_t)NN * CAP * sizeof(Pair))

// Single cooperative kernel: phase 1 builds per-row buckets (blend applied at
// scatter), grid.sync(), phase 2 assembles 8 half-rows per block in LDS and
// streams them out once with final normalized values. Exactly co-resident:
// 2048 blocks = 256 CU x 8 blocks (16KB LDS, <=64 VGPR via launch_bounds).
__global__ __launch_bounds__(256, 8) void fused_kernel(
        const int* __restrict__ rows_s, const int* __restrict__ cols_s,
        const float* __restrict__ vals_s,
        const int* __restrict__ rows_t, const int* __restrict__ cols_t,
        const float* __restrict__ vals_t,
        const float* __restrict__ gamma,
        int* __restrict__ cnt, Pair* __restrict__ bucket,
        int* __restrict__ ovf_cnt, int4* __restrict__ ovf,
        float* __restrict__ out) {
    __shared__ float row[HALF];        // 16 KB
    __shared__ float red[4];
    int i = blockIdx.x * blockDim.x + threadIdx.x;
    int t = threadIdx.x;

    // ---- Phase 1: bucket build, one edge per thread ----
    float alpha = 1.0f / (1.0f + expf(-gamma[0]));
    {
        int r, c; float v, w;
        if (i < NE) { r = rows_s[i]; c = cols_s[i]; v = vals_s[i]; w = alpha; }
        else { int j = i - NE; r = rows_t[j]; c = cols_t[j]; v = vals_t[j]; w = 1.0f - alpha; }
        float wv = w * v;
        int pos = atomicAdd(&cnt[r], 1);
        if (pos < CAP) {
            Pair p; p.c = c; p.v = wv;
            bucket[r * CAP + pos] = p;
        } else {                        // statistically unreachable; correctness keeper
            int k = atomicAdd(ovf_cnt, 1);
            int4 e; e.x = r; e.y = c; e.z = __float_as_int(wv); e.w = 0;
            ovf[k] = e;
        }
    }

    // Agent-scope release: push bucket/cnt out of the producer XCD's L2 so
    // phase-2 readers on other XCDs see them. grid.sync provides the barrier
    // + acquire side.
    __threadfence();
    cooperative_groups::this_grid().sync();

    // ---- Phase 2: 8 half-rows per block (block b owns rows 4b..4b+3) ----
    int no = *ovf_cnt;
    for (int step = 0; step < 8; ++step) {
        int hb = blockIdx.x * 8 + step;
        int r = hb >> 1;
        int base = (hb & 1) << 12;     // 0 or 4096

        f4* row4 = (f4*)row;
        #pragma unroll
        for (int k = t; k < HALF / 4; k += 256) {
            f4 z = {0.f, 0.f, 0.f, 0.f};
            row4[k] = z;
        }
        int n = cnt[r];
        int nb = n < CAP ? n : CAP;
        __syncthreads();

        float part = 0.0f;
        for (int k = t; k < nb; k += 256) {
            Pair p = bucket[r * CAP + k];
            part += p.v;               // full row sum (both halves scan all pairs)
            int cl = p.c - base;
            if ((unsigned)cl < HALF) atomicAdd(&row[cl], p.v);
        }
        if (no > 0) {                  // cold path, normally 0 entries
            for (int k = t; k < no; k += 256) {
                int4 e = ovf[k];
                if (e.x == r) {
                    float v = __int_as_float(e.z);
                    part += v;
                    int cl = e.y - base;
                    if ((unsigned)cl < HALF) atomicAdd(&row[cl], v);
                }
            }
        }

        #pragma unroll
        for (int o = 32; o > 0; o >>= 1) part += __shfl_down(part, o, 64);
        if ((t & 63) == 0) red[t >> 6] = part;
        __syncthreads();               // also fences the LDS scatter atomics
        float total = red[0] + red[1] + red[2] + red[3];
        float inv = (total == 0.0f) ? 1.0f : 1.0f / total;

        f4* out4 = (f4*)(out + (size_t)r * NN + base);
        #pragma unroll
        for (int k = t; k < HALF / 4; k += 256) {
            f4 x = row4[k];
            x *= inv;
            __builtin_nontemporal_store(x, &out4[k]);
        }
        __syncthreads();               // row[]/red[] reuse guard for next step
    }
}

extern "C" void kernel_launch(void* const* d_in, const int* in_sizes, int n_in,
                              void* d_out, int out_size, void* d_ws, size_t ws_size,
                              hipStream_t stream) {
    const int*   rows_s = (const int*)  d_in[0];
    const int*   cols_s = (const int*)  d_in[1];
    const float* vals_s = (const float*)d_in[2];
    const int*   rows_t = (const int*)  d_in[3];
    const int*   cols_t = (const int*)  d_in[4];
    const float* vals_t = (const float*)d_in[5];
    const float* gamma  = (const float*)d_in[6];

    float* out     = (float*)d_out;
    char*  ws      = (char*)d_ws;
    int*   cnt     = (int*)ws;                    // [NN]
    int*   ovf_cnt = (int*)(ws + 32768);          // [1]
    Pair*  bucket  = (Pair*)(ws + BK_OFF);        // [NN*CAP]
    int4*  ovf     = (int4*)(ws + OV_OFF);        // [8192]

    // Zero cursors + overflow counter (ws is poisoned with 0xAA).
    (void)hipMemsetAsync(ws, 0, 32772, stream);

    void* args[] = { &rows_s, &cols_s, &vals_s, &rows_t, &cols_t, &vals_t,
                     &gamma, &cnt, &bucket, &ovf_cnt, &ovf, &out };
    (void)hipLaunchCooperativeKernel((const void*)fused_kernel,
                                     dim3(TOTAL / 256), dim3(256),
                                     args, 0, stream);
}

// Round 7
// 311.366 us; speedup vs baseline: 2.2684x; 2.2684x over previous
//
#include <hip/hip_runtime.h>
#include <math.h>

#define NN 8192        // n_nodes
#define NE 262144      // edges per adjacency list
#define TOTAL (2*NE)   // 524288
#define CAP 128        // bucket capacity per row (mean 64, sd 8; max ~95)

typedef float f4 __attribute__((ext_vector_type(4)));   // native vec: OK for nontemporal builtins

struct Pair { int c; float v; };

// Workspace layout (bytes):
//   [0, 32768)              cnt[8192] row cursors
//   [32768, 32772)          ovf_cnt
//   [65536, 65536+8MB)      bucket Pair[8192][128]
//   [65536+8MB, +128KB)     ovf int4[8192]  (r, c, bits(w*v), 0)
#define BK_OFF (65536)
#define OV_OFF (65536 + (size_t)NN * CAP * 8)

// Single-pass bucket build: blend weight applied at scatter time.
// i<NE handles list s, else list t — branch is block-uniform (256 | NE).
__global__ __launch_bounds__(256) void fill_kernel(
        const int* __restrict__ rows_s, const int* __restrict__ cols_s,
        const float* __restrict__ vals_s,
        const int* __restrict__ rows_t, const int* __restrict__ cols_t,
        const float* __restrict__ vals_t,
        const float* __restrict__ gamma,
        int* __restrict__ cnt, Pair* __restrict__ bucket,
        int* __restrict__ ovf_cnt, int4* __restrict__ ovf) {
    int i = blockIdx.x * blockDim.x + threadIdx.x;
    float alpha = 1.0f / (1.0f + expf(-gamma[0]));
    int r, c; float v, w;
    if (i < NE) { r = rows_s[i]; c = cols_s[i]; v = vals_s[i]; w = alpha; }
    else { int j = i - NE; r = rows_t[j]; c = cols_t[j]; v = vals_t[j]; w = 1.0f - alpha; }
    float wv = w * v;
    int pos = atomicAdd(&cnt[r], 1);
    if (pos < CAP) {
        Pair p; p.c = c; p.v = wv;
        bucket[r * CAP + pos] = p;
    } else {
        // Statistically unreachable at these sizes; kept for correctness.
        int k = atomicAdd(ovf_cnt, 1);
        int4 e; e.x = r; e.y = c; e.z = __float_as_int(wv); e.w = 0;
        ovf[k] = e;
    }
}

// One block per output row, 8192 independent blocks — block-level parallelism
// hides the store-drain latency that the fused cooperative version (R6)
// exposed 7x by serializing 8 steps per block behind vmcnt(0) barriers.
__global__ __launch_bounds__(256) void row_kernel(
        const int* __restrict__ cnt, const Pair* __restrict__ bucket,
        const int* __restrict__ ovf_cnt, const int4* __restrict__ ovf,
        float* __restrict__ out) {
    __shared__ float row[NN];          // 32 KB
    __shared__ float red[4];
    int r = blockIdx.x;
    int t = threadIdx.x;

    f4* row4 = (f4*)row;
    #pragma unroll
    for (int k = t; k < NN / 4; k += 256) {
        f4 z = {0.f, 0.f, 0.f, 0.f};
        row4[k] = z;
    }
    int n = cnt[r];
    int nb = n < CAP ? n : CAP;
    __syncthreads();

    float part = 0.0f;
    for (int k = t; k < nb; k += 256) {
        Pair p = bucket[r * CAP + k];
        part += p.v;
        atomicAdd(&row[p.c], p.v);
    }
    int no = *ovf_cnt;
    if (no > 0) {                       // cold path, normally 0 entries
        for (int k = t; k < no; k += 256) {
            int4 e = ovf[k];
            if (e.x == r) {
                float v = __int_as_float(e.z);
                part += v;
                atomicAdd(&row[e.y], v);
            }
        }
    }

    #pragma unroll
    for (int o = 32; o > 0; o >>= 1) part += __shfl_down(part, o, 64);
    if ((t & 63) == 0) red[t >> 6] = part;
    __syncthreads();                    // also fences the LDS scatter atomics
    float total = red[0] + red[1] + red[2] + red[3];
    float inv = (total == 0.0f) ? 1.0f : 1.0f / total;

    f4* out4 = (f4*)(out + (size_t)r * NN);
    #pragma unroll
    for (int k = t; k < NN / 4; k += 256) {
        f4 x = row4[k];
        x *= inv;
        __builtin_nontemporal_store(x, &out4[k]);
    }
}

extern "C" void kernel_launch(void* const* d_in, const int* in_sizes, int n_in,
                              void* d_out, int out_size, void* d_ws, size_t ws_size,
                              hipStream_t stream) {
    const int*   rows_s = (const int*)  d_in[0];
    const int*   cols_s = (const int*)  d_in[1];
    const float* vals_s = (const float*)d_in[2];
    const int*   rows_t = (const int*)  d_in[3];
    const int*   cols_t = (const int*)  d_in[4];
    const float* vals_t = (const float*)d_in[5];
    const float* gamma  = (const float*)d_in[6];

    float* out     = (float*)d_out;
    char*  ws      = (char*)d_ws;
    int*   cnt     = (int*)ws;                    // [NN]
    int*   ovf_cnt = (int*)(ws + 32768);          // [1]
    Pair*  bucket  = (Pair*)(ws + BK_OFF);        // [NN*CAP]
    int4*  ovf     = (int4*)(ws + OV_OFF);        // [8192]

    // Zero cursors + overflow counter (ws is poisoned with 0xAA).
    (void)hipMemsetAsync(ws, 0, 32772, stream);

    fill_kernel<<<TOTAL / 256, 256, 0, stream>>>(rows_s, cols_s, vals_s,
                                                 rows_t, cols_t, vals_t,
                                                 gamma, cnt, bucket, ovf_cnt, ovf);
    row_kernel<<<NN, 256, 0, stream>>>(cnt, bucket, ovf_cnt, ovf, out);
}